// Round 1
// baseline (794.948 us; speedup 1.0000x reference)
//
#include <hip/hip_runtime.h>

#define N_NODES 50000
#define N_EDGES 400000
#define IN_DIM  128
#define HE      512      // edge hidden
#define HS      256      // self hidden
#define OUT_HALF 128
#define OUT_DIM 256
#define N_TYPES 16

typedef __attribute__((ext_vector_type(8))) short short8;
typedef __attribute__((ext_vector_type(4))) float floatx4;

__device__ __forceinline__ float bf2f(unsigned short u) {
    union { unsigned int i; float f; } v; v.i = ((unsigned int)u) << 16; return v.f;
}
__device__ __forceinline__ unsigned short f2bf(float f) {
    union { float f; unsigned int i; } v; v.f = f;
    unsigned int b = v.i;
    return (unsigned short)((b + 0x7FFFu + ((b >> 16) & 1u)) >> 16);
}

// ---------------- prep kernels ----------------

__global__ void k_cvt_feat(const float* __restrict__ src, unsigned short* __restrict__ dst, int n) {
    int i = (blockIdx.x * blockDim.x + threadIdx.x) * 4;
    int stride = gridDim.x * blockDim.x * 4;
    for (; i < n; i += stride) {
        float4 v = *(const float4*)&src[i];
        ushort4 o;
        o.x = f2bf(v.x); o.y = f2bf(v.y); o.z = f2bf(v.z); o.w = f2bf(v.w);
        *(ushort4*)&dst[i] = o;
    }
}

// T[16][512] = e_emb @ W1e[:128,:] + b1e   (f32, tiny)
__global__ void k_prep_T(const float* __restrict__ e_emb, const float* __restrict__ W1e,
                         const float* __restrict__ b1e, float* __restrict__ T) {
    int tid = blockIdx.x * 256 + threadIdx.x;   // 0..8191
    int typ = tid >> 9, col = tid & 511;
    float acc = b1e[col];
    for (int k = 0; k < 128; ++k)
        acc += e_emb[typ * 128 + k] * W1e[k * 512 + col];
    T[tid] = acc;
}

// dst[c*K + k] = bf16(src[k*Ncols + c])   (N-major transpose for MFMA B-frag loads)
__global__ void k_transpose_bf16(const float* __restrict__ src, unsigned short* __restrict__ dst,
                                 int K, int Ncols) {
    int tid = blockIdx.x * 256 + threadIdx.x;
    if (tid >= K * Ncols) return;
    int c = tid / K, k = tid - c * K;
    dst[tid] = f2bf(src[k * Ncols + c]);
}

// ---------------- G = features @ W1e_bot   [N,512] bf16 ----------------
// block: 256 thr = 4 waves; tile M=64 nodes x N=128 cols; grid.y = 4 col-chunks
__global__ __launch_bounds__(256) void k_gemm_G(const unsigned short* __restrict__ fb,
                                                const unsigned short* __restrict__ W1ebT,
                                                unsigned short* __restrict__ G) {
    __shared__ unsigned short fbs[64 * 128];   // 16 KB, XOR-swizzled chunks
    int t = threadIdx.x;
    int mbase = blockIdx.x * 64;
    int nbase = blockIdx.y * 128;
    {
        int row = t >> 2, seg = t & 3;
        int node = mbase + row; if (node >= N_NODES) node = N_NODES - 1;
        const unsigned short* p = &fb[node * 128 + seg * 32];
        #pragma unroll
        for (int i = 0; i < 4; ++i) {
            int c = seg * 4 + i;
            int cp = c ^ (row & 7);
            *(short8*)&fbs[row * 128 + cp * 8] = *(const short8*)&p[i * 8];
        }
    }
    __syncthreads();
    int lane = t & 63, wave = t >> 6;
    int r = lane & 15, quad = lane >> 4;
    floatx4 acc[8];
    #pragma unroll
    for (int i = 0; i < 8; ++i) acc[i] = (floatx4){0.f, 0.f, 0.f, 0.f};
    #pragma unroll
    for (int ks = 0; ks < 4; ++ks) {
        int row = wave * 16 + r;
        int cp = (ks * 4 + quad) ^ (row & 7);
        short8 a = *(const short8*)&fbs[row * 128 + cp * 8];
        int k0 = ks * 32 + quad * 8;
        #pragma unroll
        for (int ct = 0; ct < 8; ++ct) {
            short8 b = *(const short8*)&W1ebT[(nbase + ct * 16 + r) * 128 + k0];
            acc[ct] = __builtin_amdgcn_mfma_f32_16x16x32_bf16(a, b, acc[ct], 0, 0, 0);
        }
    }
    #pragma unroll
    for (int ct = 0; ct < 8; ++ct)
        #pragma unroll
        for (int p = 0; p < 4; ++p) {
            int node = mbase + wave * 16 + quad * 4 + p;
            if (node < N_NODES)
                G[node * 512 + nbase + ct * 16 + r] = f2bf(acc[ct][p]);
        }
}

// ---------------- self MLP: out[:, :128] = relu(f@W1s+b1s)@W2s + b2s ----------------
__global__ __launch_bounds__(256) void k_self(const unsigned short* __restrict__ fb,
                                              const unsigned short* __restrict__ W1sT,
                                              const float* __restrict__ b1s,
                                              const unsigned short* __restrict__ W2sT,
                                              const float* __restrict__ b2s,
                                              float* __restrict__ out) {
    __shared__ unsigned short fbs[64 * 128];   // 16 KB
    __shared__ unsigned short hss[64 * 256];   // 32 KB
    int t = threadIdx.x;
    int mbase = blockIdx.x * 64;
    {
        int row = t >> 2, seg = t & 3;
        int node = mbase + row; if (node >= N_NODES) node = N_NODES - 1;
        const unsigned short* p = &fb[node * 128 + seg * 32];
        #pragma unroll
        for (int i = 0; i < 4; ++i) {
            int c = seg * 4 + i;
            int cp = c ^ (row & 7);
            *(short8*)&fbs[row * 128 + cp * 8] = *(const short8*)&p[i * 8];
        }
    }
    __syncthreads();
    int lane = t & 63, wave = t >> 6;
    int r = lane & 15, quad = lane >> 4;

    // layer 1: 16 rows x 256 cols per wave
    floatx4 acc1[16];
    #pragma unroll
    for (int i = 0; i < 16; ++i) acc1[i] = (floatx4){0.f, 0.f, 0.f, 0.f};
    #pragma unroll
    for (int ks = 0; ks < 4; ++ks) {
        int row = wave * 16 + r;
        int cp = (ks * 4 + quad) ^ (row & 7);
        short8 a = *(const short8*)&fbs[row * 128 + cp * 8];
        int k0 = ks * 32 + quad * 8;
        #pragma unroll
        for (int ct = 0; ct < 16; ++ct) {
            short8 b = *(const short8*)&W1sT[(ct * 16 + r) * 128 + k0];
            acc1[ct] = __builtin_amdgcn_mfma_f32_16x16x32_bf16(a, b, acc1[ct], 0, 0, 0);
        }
    }
    #pragma unroll
    for (int ct = 0; ct < 16; ++ct)
        #pragma unroll
        for (int p = 0; p < 4; ++p) {
            int lrow = wave * 16 + quad * 4 + p;
            int col = ct * 16 + r;
            float v = fmaxf(acc1[ct][p] + b1s[col], 0.f);
            int cp = (col >> 3) ^ (lrow & 7);
            hss[lrow * 256 + cp * 8 + (col & 7)] = f2bf(v);
        }
    __syncthreads();

    // layer 2: 16 rows x 128 cols per wave, K=256
    floatx4 acc2[8];
    #pragma unroll
    for (int i = 0; i < 8; ++i) acc2[i] = (floatx4){0.f, 0.f, 0.f, 0.f};
    #pragma unroll
    for (int ks = 0; ks < 8; ++ks) {
        int row = wave * 16 + r;
        int cp = (ks * 4 + quad) ^ (row & 7);
        short8 a = *(const short8*)&hss[row * 256 + cp * 8];
        int k0 = ks * 32 + quad * 8;
        #pragma unroll
        for (int ct = 0; ct < 8; ++ct) {
            short8 b = *(const short8*)&W2sT[(ct * 16 + r) * 256 + k0];
            acc2[ct] = __builtin_amdgcn_mfma_f32_16x16x32_bf16(a, b, acc2[ct], 0, 0, 0);
        }
    }
    #pragma unroll
    for (int ct = 0; ct < 8; ++ct)
        #pragma unroll
        for (int p = 0; p < 4; ++p) {
            int node = mbase + wave * 16 + quad * 4 + p;
            if (node < N_NODES) {
                int col = ct * 16 + r;
                out[(size_t)node * 256 + col] = acc2[ct][p] + b2s[col];
            }
        }
}

// ---------------- edge: m = relu(G[src]+T[type]) @ W2e + b2e, atomic scatter ----------------
// block: 256 thr = 4 waves; 64 edges/block; h tile 64x512 bf16 in 64 KB LDS
__global__ __launch_bounds__(256) void k_edge(const unsigned short* __restrict__ G,
                                              const float* __restrict__ T,
                                              const int* __restrict__ edge_src,
                                              const int* __restrict__ edge_dst,
                                              const int* __restrict__ edge_type,
                                              const unsigned short* __restrict__ W2eT,
                                              const float* __restrict__ b2e,
                                              float* __restrict__ out) {
    __shared__ unsigned short hls[64 * 512];   // 64 KB
    int t = threadIdx.x;
    int ebase = blockIdx.x * 64;
    {
        int erow = t >> 2, seg = t & 3;
        int e = ebase + erow;
        int src = edge_src[e];
        int typ = edge_type[e];
        const unsigned short* gp = &G[(size_t)src * 512 + seg * 128];
        const float* tp = &T[typ * 512 + seg * 128];
        #pragma unroll
        for (int i = 0; i < 16; ++i) {
            short8 g = *(const short8*)&gp[i * 8];
            float4 t0 = *(const float4*)&tp[i * 8];
            float4 t1 = *(const float4*)&tp[i * 8 + 4];
            short8 hv;
            hv[0] = (short)f2bf(fmaxf(bf2f((unsigned short)g[0]) + t0.x, 0.f));
            hv[1] = (short)f2bf(fmaxf(bf2f((unsigned short)g[1]) + t0.y, 0.f));
            hv[2] = (short)f2bf(fmaxf(bf2f((unsigned short)g[2]) + t0.z, 0.f));
            hv[3] = (short)f2bf(fmaxf(bf2f((unsigned short)g[3]) + t0.w, 0.f));
            hv[4] = (short)f2bf(fmaxf(bf2f((unsigned short)g[4]) + t1.x, 0.f));
            hv[5] = (short)f2bf(fmaxf(bf2f((unsigned short)g[5]) + t1.y, 0.f));
            hv[6] = (short)f2bf(fmaxf(bf2f((unsigned short)g[6]) + t1.z, 0.f));
            hv[7] = (short)f2bf(fmaxf(bf2f((unsigned short)g[7]) + t1.w, 0.f));
            int c = seg * 16 + i;
            int cp = c ^ (erow & 7);
            *(short8*)&hls[erow * 512 + cp * 8] = hv;
        }
    }
    __syncthreads();
    int lane = t & 63, wave = t >> 6;
    int r = lane & 15, quad = lane >> 4;
    floatx4 acc[8];
    #pragma unroll
    for (int i = 0; i < 8; ++i) acc[i] = (floatx4){0.f, 0.f, 0.f, 0.f};
    #pragma unroll
    for (int ks = 0; ks < 16; ++ks) {
        int row = wave * 16 + r;
        int cp = (ks * 4 + quad) ^ (row & 7);
        short8 a = *(const short8*)&hls[row * 512 + cp * 8];
        int k0 = ks * 32 + quad * 8;
        #pragma unroll
        for (int ct = 0; ct < 8; ++ct) {
            short8 b = *(const short8*)&W2eT[(ct * 16 + r) * 512 + k0];
            acc[ct] = __builtin_amdgcn_mfma_f32_16x16x32_bf16(a, b, acc[ct], 0, 0, 0);
        }
    }
    float b2v[8];
    #pragma unroll
    for (int ct = 0; ct < 8; ++ct) b2v[ct] = b2e[ct * 16 + r];
    #pragma unroll
    for (int p = 0; p < 4; ++p) {
        int er = ebase + wave * 16 + quad * 4 + p;
        int dst = edge_dst[er];
        float* op = &out[(size_t)dst * 256 + 128];
        #pragma unroll
        for (int ct = 0; ct < 8; ++ct)
            atomicAdd(&op[ct * 16 + r], acc[ct][p] + b2v[ct]);
    }
}

// ---------------- launch ----------------

extern "C" void kernel_launch(void* const* d_in, const int* in_sizes, int n_in,
                              void* d_out, int out_size, void* d_ws, size_t ws_size,
                              hipStream_t stream) {
    const float* features  = (const float*)d_in[0];
    const int*   edge_src  = (const int*)d_in[1];
    const int*   edge_dst  = (const int*)d_in[2];
    const int*   edge_type = (const int*)d_in[3];
    const float* e_emb     = (const float*)d_in[4];
    const float* W1e       = (const float*)d_in[5];
    const float* b1e       = (const float*)d_in[6];
    const float* W2e       = (const float*)d_in[7];
    const float* b2e       = (const float*)d_in[8];
    // const float* W1s    = d_in[9], b1s = d_in[10], W2s = d_in[11], b2s = d_in[12]
    const float* W1s       = (const float*)d_in[9];
    const float* b1s       = (const float*)d_in[10];
    const float* W2s       = (const float*)d_in[11];
    const float* b2s       = (const float*)d_in[12];
    float* out = (float*)d_out;

    char* ws = (char*)d_ws;
    size_t off = 0;
    auto alloc = [&](size_t bytes) {
        char* p = ws + off;
        off += (bytes + 255) & ~(size_t)255;
        return p;
    };
    unsigned short* fb    = (unsigned short*)alloc((size_t)N_NODES * 128 * 2);
    unsigned short* G     = (unsigned short*)alloc((size_t)N_NODES * 512 * 2);
    float*          T     = (float*)alloc(16 * 512 * 4);
    unsigned short* W1ebT = (unsigned short*)alloc(512 * 128 * 2);
    unsigned short* W2eT  = (unsigned short*)alloc(128 * 512 * 2);
    unsigned short* W1sT  = (unsigned short*)alloc(256 * 128 * 2);
    unsigned short* W2sT  = (unsigned short*)alloc(128 * 256 * 2);

    k_cvt_feat<<<1024, 256, 0, stream>>>(features, fb, N_NODES * 128);
    k_prep_T<<<32, 256, 0, stream>>>(e_emb, W1e, b1e, T);
    k_transpose_bf16<<<(512 * 128 + 255) / 256, 256, 0, stream>>>(W1e + 128 * 512, W1ebT, 128, 512);
    k_transpose_bf16<<<(128 * 512 + 255) / 256, 256, 0, stream>>>(W2e, W2eT, 512, 128);
    k_transpose_bf16<<<(256 * 128 + 255) / 256, 256, 0, stream>>>(W1s, W1sT, 128, 256);
    k_transpose_bf16<<<(128 * 256 + 255) / 256, 256, 0, stream>>>(W2s, W2sT, 256, 128);

    hipMemsetAsync(d_out, 0, (size_t)out_size * sizeof(float), stream);

    k_gemm_G<<<dim3((N_NODES + 63) / 64, 4), 256, 0, stream>>>(fb, W1ebT, G);
    k_self<<<(N_NODES + 63) / 64, 256, 0, stream>>>(fb, W1sT, b1s, W2sT, b2s, out);
    k_edge<<<N_EDGES / 64, 256, 0, stream>>>(G, T, edge_src, edge_dst, edge_type, W2eT, b2e, out);
}

// Round 2
// 553.298 us; speedup vs baseline: 1.4367x; 1.4367x over previous
//
#include <hip/hip_runtime.h>

#define N_NODES 50000
#define N_EDGES 400000
#define IN_DIM  128
#define HE      512
#define OUT_HALF 128
#define N_TYPES 16

#define N_PAD   50176        // 196 * 256
#define NBLK    196

typedef __attribute__((ext_vector_type(8))) short short8;
typedef __attribute__((ext_vector_type(4))) float floatx4;

__device__ __forceinline__ float bf2f(unsigned short u) {
    union { unsigned int i; float f; } v; v.i = ((unsigned int)u) << 16; return v.f;
}
__device__ __forceinline__ unsigned short f2bf(float f) {
    union { float f; unsigned int i; } v; v.f = f;
    unsigned int b = v.i;
    return (unsigned short)((b + 0x7FFFu + ((b >> 16) & 1u)) >> 16);
}

// ---------------- prep kernels ----------------

__global__ void k_cvt_feat(const float* __restrict__ src, unsigned short* __restrict__ dst, int n) {
    int i = (blockIdx.x * blockDim.x + threadIdx.x) * 4;
    int stride = gridDim.x * blockDim.x * 4;
    for (; i < n; i += stride) {
        float4 v = *(const float4*)&src[i];
        ushort4 o;
        o.x = f2bf(v.x); o.y = f2bf(v.y); o.z = f2bf(v.z); o.w = f2bf(v.w);
        *(ushort4*)&dst[i] = o;
    }
}

// Tb[16][512] = bf16(e_emb @ W1e[:128,:] + b1e)
__global__ void k_prep_T(const float* __restrict__ e_emb, const float* __restrict__ W1e,
                         const float* __restrict__ b1e, unsigned short* __restrict__ Tb) {
    int tid = blockIdx.x * 256 + threadIdx.x;   // 0..8191
    int typ = tid >> 9, col = tid & 511;
    float acc = b1e[col];
    for (int k = 0; k < 128; ++k)
        acc += e_emb[typ * 128 + k] * W1e[k * 512 + col];
    Tb[tid] = f2bf(acc);
}

// dst[c*K + k] = bf16(src[k*Ncols + c])
__global__ void k_transpose_bf16(const float* __restrict__ src, unsigned short* __restrict__ dst,
                                 int K, int Ncols) {
    int tid = blockIdx.x * 256 + threadIdx.x;
    if (tid >= K * Ncols) return;
    int c = tid / K, k = tid - c * K;
    dst[tid] = f2bf(src[k * Ncols + c]);
}

// ---------------- counting sort of edges by dst ----------------

__global__ void k_hist(const int* __restrict__ edge_dst, int* __restrict__ counts) {
    int e = blockIdx.x * 256 + threadIdx.x;
    if (e < N_EDGES) atomicAdd(&counts[edge_dst[e]], 1);
}

__global__ void k_scan1(const int* __restrict__ counts, int* __restrict__ blocksum) {
    __shared__ int s[256];
    int t = threadIdx.x;
    s[t] = counts[blockIdx.x * 256 + t];
    __syncthreads();
    for (int d = 128; d > 0; d >>= 1) {
        if (t < d) s[t] += s[t + d];
        __syncthreads();
    }
    if (t == 0) blocksum[blockIdx.x] = s[0];
}

__global__ void k_scan2(const int* __restrict__ blocksum, int* __restrict__ blockoff) {
    __shared__ int s[256];
    int t = threadIdx.x;
    int v = (t < NBLK) ? blocksum[t] : 0;
    s[t] = v;
    __syncthreads();
    for (int d = 1; d < 256; d <<= 1) {
        int x = (t >= d) ? s[t - d] : 0;
        __syncthreads();
        s[t] += x;
        __syncthreads();
    }
    if (t < NBLK) blockoff[t] = s[t] - v;   // exclusive
}

__global__ void k_scan3(const int* __restrict__ counts, const int* __restrict__ blockoff,
                        int* __restrict__ row_start, int* __restrict__ cursor) {
    __shared__ int s[256];
    int t = threadIdx.x;
    int i = blockIdx.x * 256 + t;
    int v = counts[i];
    s[t] = v;
    __syncthreads();
    for (int d = 1; d < 256; d <<= 1) {
        int x = (t >= d) ? s[t - d] : 0;
        __syncthreads();
        s[t] += x;
        __syncthreads();
    }
    int excl = s[t] - v + blockoff[blockIdx.x];
    row_start[i] = excl;
    cursor[i] = excl;
}

__global__ void k_scatter(const int* __restrict__ edge_src, const int* __restrict__ edge_dst,
                          const int* __restrict__ edge_type, int* __restrict__ cursor,
                          int* __restrict__ sorted_src, int* __restrict__ sorted_type) {
    int e = blockIdx.x * 256 + threadIdx.x;
    if (e < N_EDGES) {
        int d = edge_dst[e];
        int pos = atomicAdd(&cursor[d], 1);
        sorted_src[pos] = edge_src[e];
        sorted_type[pos] = edge_type[e];
    }
}

// ---------------- G = features @ W1e_bot   [N,512] bf16 ----------------
__global__ __launch_bounds__(256) void k_gemm_G(const unsigned short* __restrict__ fb,
                                                const unsigned short* __restrict__ W1ebT,
                                                unsigned short* __restrict__ G) {
    __shared__ unsigned short fbs[64 * 128];
    int t = threadIdx.x;
    int mbase = blockIdx.x * 64;
    int nbase = blockIdx.y * 128;
    {
        int row = t >> 2, seg = t & 3;
        int node = mbase + row; if (node >= N_NODES) node = N_NODES - 1;
        const unsigned short* p = &fb[node * 128 + seg * 32];
        #pragma unroll
        for (int i = 0; i < 4; ++i) {
            int c = seg * 4 + i;
            int cp = c ^ (row & 7);
            *(short8*)&fbs[row * 128 + cp * 8] = *(const short8*)&p[i * 8];
        }
    }
    __syncthreads();
    int lane = t & 63, wave = t >> 6;
    int r = lane & 15, quad = lane >> 4;
    floatx4 acc[8];
    #pragma unroll
    for (int i = 0; i < 8; ++i) acc[i] = (floatx4){0.f, 0.f, 0.f, 0.f};
    #pragma unroll
    for (int ks = 0; ks < 4; ++ks) {
        int row = wave * 16 + r;
        int cp = (ks * 4 + quad) ^ (row & 7);
        short8 a = *(const short8*)&fbs[row * 128 + cp * 8];
        int k0 = ks * 32 + quad * 8;
        #pragma unroll
        for (int ct = 0; ct < 8; ++ct) {
            short8 b = *(const short8*)&W1ebT[(nbase + ct * 16 + r) * 128 + k0];
            acc[ct] = __builtin_amdgcn_mfma_f32_16x16x32_bf16(a, b, acc[ct], 0, 0, 0);
        }
    }
    #pragma unroll
    for (int ct = 0; ct < 8; ++ct)
        #pragma unroll
        for (int p = 0; p < 4; ++p) {
            int node = mbase + wave * 16 + quad * 4 + p;
            if (node < N_NODES)
                G[node * 512 + nbase + ct * 16 + r] = f2bf(acc[ct][p]);
        }
}

// ---------------- self MLP: out[:, :128] ----------------
__global__ __launch_bounds__(256) void k_self(const unsigned short* __restrict__ fb,
                                              const unsigned short* __restrict__ W1sT,
                                              const float* __restrict__ b1s,
                                              const unsigned short* __restrict__ W2sT,
                                              const float* __restrict__ b2s,
                                              float* __restrict__ out) {
    __shared__ unsigned short fbs[64 * 128];
    __shared__ unsigned short hss[64 * 256];
    int t = threadIdx.x;
    int mbase = blockIdx.x * 64;
    {
        int row = t >> 2, seg = t & 3;
        int node = mbase + row; if (node >= N_NODES) node = N_NODES - 1;
        const unsigned short* p = &fb[node * 128 + seg * 32];
        #pragma unroll
        for (int i = 0; i < 4; ++i) {
            int c = seg * 4 + i;
            int cp = c ^ (row & 7);
            *(short8*)&fbs[row * 128 + cp * 8] = *(const short8*)&p[i * 8];
        }
    }
    __syncthreads();
    int lane = t & 63, wave = t >> 6;
    int r = lane & 15, quad = lane >> 4;

    floatx4 acc1[16];
    #pragma unroll
    for (int i = 0; i < 16; ++i) acc1[i] = (floatx4){0.f, 0.f, 0.f, 0.f};
    #pragma unroll
    for (int ks = 0; ks < 4; ++ks) {
        int row = wave * 16 + r;
        int cp = (ks * 4 + quad) ^ (row & 7);
        short8 a = *(const short8*)&fbs[row * 128 + cp * 8];
        int k0 = ks * 32 + quad * 8;
        #pragma unroll
        for (int ct = 0; ct < 16; ++ct) {
            short8 b = *(const short8*)&W1sT[(ct * 16 + r) * 128 + k0];
            acc1[ct] = __builtin_amdgcn_mfma_f32_16x16x32_bf16(a, b, acc1[ct], 0, 0, 0);
        }
    }
    #pragma unroll
    for (int ct = 0; ct < 16; ++ct)
        #pragma unroll
        for (int p = 0; p < 4; ++p) {
            int lrow = wave * 16 + quad * 4 + p;
            int col = ct * 16 + r;
            float v = fmaxf(acc1[ct][p] + b1s[col], 0.f);
            int cp = (col >> 3) ^ (lrow & 7);
            hss[lrow * 256 + cp * 8 + (col & 7)] = f2bf(v);
        }
    __syncthreads();

    floatx4 acc2[8];
    #pragma unroll
    for (int i = 0; i < 8; ++i) acc2[i] = (floatx4){0.f, 0.f, 0.f, 0.f};
    #pragma unroll
    for (int ks = 0; ks < 8; ++ks) {
        int row = wave * 16 + r;
        int cp = (ks * 4 + quad) ^ (row & 7);
        short8 a = *(const short8*)&hss[row * 256 + cp * 8];
        int k0 = ks * 32 + quad * 8;
        #pragma unroll
        for (int ct = 0; ct < 8; ++ct) {
            short8 b = *(const short8*)&W2sT[(ct * 16 + r) * 256 + k0];
            acc2[ct] = __builtin_amdgcn_mfma_f32_16x16x32_bf16(a, b, acc2[ct], 0, 0, 0);
        }
    }
    #pragma unroll
    for (int ct = 0; ct < 8; ++ct)
        #pragma unroll
        for (int p = 0; p < 4; ++p) {
            int node = mbase + wave * 16 + quad * 4 + p;
            if (node < N_NODES) {
                int col = ct * 16 + r;
                out[(size_t)node * 256 + col] = acc2[ct][p] + b2s[col];
            }
        }
}

// ---------------- fused aggregate + GEMM ----------------
// agg[dst] = (sum_e relu(G[src]+T[type])) @ W2e + deg*b2e  -> out[:,128:]
// block = 256 thr (4 waves), 64 dst nodes. Phase 1: each wave aggregates 16
// nodes (one at a time, all 64 lanes = 512 dims, 8 f32 acc/lane), writes bf16
// H-tile to LDS. Phase 2: MFMA [64x512]x[512x128] from LDS, plain stores.
__global__ __launch_bounds__(256) void k_aggemm(const unsigned short* __restrict__ G,
                                                const unsigned short* __restrict__ Tb,
                                                const int* __restrict__ row_start,
                                                const int* __restrict__ sorted_src,
                                                const int* __restrict__ sorted_type,
                                                const unsigned short* __restrict__ W2eT,
                                                const float* __restrict__ b2e,
                                                float* __restrict__ out) {
    __shared__ unsigned short hls[64 * 512];   // 64 KB
    __shared__ int degs[64];
    int t = threadIdx.x, lane = t & 63, wave = t >> 6;
    int nbase = blockIdx.x * 64;

    for (int j = 0; j < 16; ++j) {
        int row = wave * 16 + j;
        int node = nbase + row;
        float acc[8] = {0.f, 0.f, 0.f, 0.f, 0.f, 0.f, 0.f, 0.f};
        int deg = 0;
        if (node < N_NODES) {
            int beg = row_start[node], end = row_start[node + 1];
            deg = end - beg;
            for (int e = beg; e < end; ++e) {
                int src = sorted_src[e];
                int typ = sorted_type[e];
                short8 g  = *(const short8*)&G[(size_t)src * 512 + lane * 8];
                short8 tv = *(const short8*)&Tb[typ * 512 + lane * 8];
                #pragma unroll
                for (int i = 0; i < 8; ++i)
                    acc[i] += fmaxf(bf2f((unsigned short)g[i]) + bf2f((unsigned short)tv[i]), 0.f);
            }
        }
        if (lane == 0) degs[row] = deg;
        short8 hv;
        #pragma unroll
        for (int i = 0; i < 8; ++i) hv[i] = (short)f2bf(acc[i]);
        int cp = lane ^ (row & 7);
        *(short8*)&hls[row * 512 + cp * 8] = hv;
    }
    __syncthreads();

    int r = lane & 15, quad = lane >> 4;
    floatx4 acc[8];
    #pragma unroll
    for (int i = 0; i < 8; ++i) acc[i] = (floatx4){0.f, 0.f, 0.f, 0.f};
    #pragma unroll
    for (int ks = 0; ks < 16; ++ks) {
        int row = wave * 16 + r;
        int cp = (ks * 4 + quad) ^ (row & 7);
        short8 a = *(const short8*)&hls[row * 512 + cp * 8];
        int k0 = ks * 32 + quad * 8;
        #pragma unroll
        for (int ct = 0; ct < 8; ++ct) {
            short8 b = *(const short8*)&W2eT[(ct * 16 + r) * 512 + k0];
            acc[ct] = __builtin_amdgcn_mfma_f32_16x16x32_bf16(a, b, acc[ct], 0, 0, 0);
        }
    }
    float b2v[8];
    #pragma unroll
    for (int ct = 0; ct < 8; ++ct) b2v[ct] = b2e[ct * 16 + r];
    #pragma unroll
    for (int p = 0; p < 4; ++p) {
        int row = wave * 16 + quad * 4 + p;
        int node = nbase + row;
        if (node < N_NODES) {
            float dg = (float)degs[row];
            float* op = &out[(size_t)node * 256 + 128];
            #pragma unroll
            for (int ct = 0; ct < 8; ++ct)
                op[ct * 16 + r] = acc[ct][p] + dg * b2v[ct];
        }
    }
}

// ---------------- launch ----------------

extern "C" void kernel_launch(void* const* d_in, const int* in_sizes, int n_in,
                              void* d_out, int out_size, void* d_ws, size_t ws_size,
                              hipStream_t stream) {
    const float* features  = (const float*)d_in[0];
    const int*   edge_src  = (const int*)d_in[1];
    const int*   edge_dst  = (const int*)d_in[2];
    const int*   edge_type = (const int*)d_in[3];
    const float* e_emb     = (const float*)d_in[4];
    const float* W1e       = (const float*)d_in[5];
    const float* b1e       = (const float*)d_in[6];
    const float* W2e       = (const float*)d_in[7];
    const float* b2e       = (const float*)d_in[8];
    const float* W1s       = (const float*)d_in[9];
    const float* b1s       = (const float*)d_in[10];
    const float* W2s       = (const float*)d_in[11];
    const float* b2s       = (const float*)d_in[12];
    float* out = (float*)d_out;

    char* ws = (char*)d_ws;
    size_t off = 0;
    auto alloc = [&](size_t bytes) {
        char* p = ws + off;
        off += (bytes + 255) & ~(size_t)255;
        return p;
    };
    unsigned short* fb       = (unsigned short*)alloc((size_t)N_NODES * 128 * 2);
    unsigned short* G        = (unsigned short*)alloc((size_t)N_NODES * 512 * 2);
    unsigned short* Tb       = (unsigned short*)alloc(16 * 512 * 2);
    unsigned short* W1ebT    = (unsigned short*)alloc(512 * 128 * 2);
    unsigned short* W2eT     = (unsigned short*)alloc(128 * 512 * 2);
    unsigned short* W1sT     = (unsigned short*)alloc(256 * 128 * 2);
    unsigned short* W2sT     = (unsigned short*)alloc(128 * 256 * 2);
    int* counts     = (int*)alloc((size_t)N_PAD * 4);
    int* row_start  = (int*)alloc((size_t)N_PAD * 4);
    int* cursor     = (int*)alloc((size_t)N_PAD * 4);
    int* blocksum   = (int*)alloc(256 * 4);
    int* blockoff   = (int*)alloc(256 * 4);
    int* sorted_src = (int*)alloc((size_t)N_EDGES * 4);
    int* sorted_typ = (int*)alloc((size_t)N_EDGES * 4);

    hipMemsetAsync(counts, 0, (size_t)N_PAD * 4, stream);

    k_cvt_feat<<<1024, 256, 0, stream>>>(features, fb, N_NODES * 128);
    k_prep_T<<<32, 256, 0, stream>>>(e_emb, W1e, b1e, Tb);
    k_transpose_bf16<<<(512 * 128 + 255) / 256, 256, 0, stream>>>(W1e + 128 * 512, W1ebT, 128, 512);
    k_transpose_bf16<<<(128 * 512 + 255) / 256, 256, 0, stream>>>(W2e, W2eT, 512, 128);
    k_transpose_bf16<<<(256 * 128 + 255) / 256, 256, 0, stream>>>(W1s, W1sT, 128, 256);
    k_transpose_bf16<<<(128 * 256 + 255) / 256, 256, 0, stream>>>(W2s, W2sT, 256, 128);

    k_hist<<<(N_EDGES + 255) / 256, 256, 0, stream>>>(edge_dst, counts);
    k_scan1<<<NBLK, 256, 0, stream>>>(counts, blocksum);
    k_scan2<<<1, 256, 0, stream>>>(blocksum, blockoff);
    k_scan3<<<NBLK, 256, 0, stream>>>(counts, blockoff, row_start, cursor);
    k_scatter<<<(N_EDGES + 255) / 256, 256, 0, stream>>>(edge_src, edge_dst, edge_type,
                                                         cursor, sorted_src, sorted_typ);

    k_gemm_G<<<dim3((N_NODES + 63) / 64, 4), 256, 0, stream>>>(fb, W1ebT, G);
    k_self<<<(N_NODES + 63) / 64, 256, 0, stream>>>(fb, W1sT, b1s, W2sT, b2s, out);
    k_aggemm<<<(N_NODES + 63) / 64, 256, 0, stream>>>(G, Tb, row_start, sorted_src, sorted_typ,
                                                      W2eT, b2e, out);
}

// Round 3
// 436.866 us; speedup vs baseline: 1.8197x; 1.2665x over previous
//
#include <hip/hip_runtime.h>

#define N_NODES 50000
#define N_EDGES 400000
#define IN_DIM  128
#define HE      512
#define OUT_HALF 128
#define N_TYPES 16

#define N_PAD   50176        // 196 * 256
#define NBLK    196

typedef __attribute__((ext_vector_type(8))) short short8;
typedef __attribute__((ext_vector_type(4))) float floatx4;

__device__ __forceinline__ float bf2f(unsigned short u) {
    union { unsigned int i; float f; } v; v.i = ((unsigned int)u) << 16; return v.f;
}
__device__ __forceinline__ unsigned short f2bf(float f) {
    union { float f; unsigned int i; } v; v.f = f;
    unsigned int b = v.i;
    return (unsigned short)((b + 0x7FFFu + ((b >> 16) & 1u)) >> 16);
}

// ---------------- prep ----------------

__global__ void k_cvt_feat(const float* __restrict__ src, unsigned short* __restrict__ dst, int n) {
    int i = (blockIdx.x * blockDim.x + threadIdx.x) * 4;
    int stride = gridDim.x * blockDim.x * 4;
    for (; i < n; i += stride) {
        float4 v = *(const float4*)&src[i];
        ushort4 o;
        o.x = f2bf(v.x); o.y = f2bf(v.y); o.z = f2bf(v.z); o.w = f2bf(v.w);
        *(ushort4*)&dst[i] = o;
    }
}

__device__ __forceinline__ void tr_seg(const float* __restrict__ src, unsigned short* __restrict__ dst,
                                       int K, int Ncols, int idx) {
    int c = idx / K, k = idx - c * K;
    dst[idx] = f2bf(src[k * Ncols + c]);
}

// One fused weight-prep kernel. Segments (all 256-aligned):
//   [0,8192)        Tb[16][512] = bf16(e_emb @ W1e_top + b1e)
//   [8192,73728)    W1ebT [512][128]
//   [73728,139264)  W2eT  [128][512]
//   [139264,172032) W1sT  [256][128]
//   [172032,204800) W2sT  [128][256]
__global__ void k_prep_w(const float* __restrict__ e_emb, const float* __restrict__ W1e,
                         const float* __restrict__ b1e, const float* __restrict__ W2e,
                         const float* __restrict__ W1s, const float* __restrict__ W2s,
                         unsigned short* __restrict__ Tb, unsigned short* __restrict__ W1ebT,
                         unsigned short* __restrict__ W2eT, unsigned short* __restrict__ W1sT,
                         unsigned short* __restrict__ W2sT) {
    int tid = blockIdx.x * 256 + threadIdx.x;
    if (tid < 8192) {
        int typ = tid >> 9, col = tid & 511;
        float acc = b1e[col];
        for (int k = 0; k < 128; ++k)
            acc += e_emb[typ * 128 + k] * W1e[k * 512 + col];
        Tb[tid] = f2bf(acc);
    } else if (tid < 73728) {
        tr_seg(W1e + 128 * 512, W1ebT, 128, 512, tid - 8192);
    } else if (tid < 139264) {
        tr_seg(W2e, W2eT, 512, 128, tid - 73728);
    } else if (tid < 172032) {
        tr_seg(W1s, W1sT, 128, 256, tid - 139264);
    } else if (tid < 204800) {
        tr_seg(W2s, W2sT, 256, 128, tid - 172032);
    }
}

// ---------------- counting sort of edges by dst ----------------

__global__ void k_hist(const int* __restrict__ edge_dst, int* __restrict__ counts) {
    int e = blockIdx.x * 256 + threadIdx.x;
    if (e < N_EDGES) atomicAdd(&counts[edge_dst[e]], 1);
}

__global__ void k_scan1(const int* __restrict__ counts, int* __restrict__ blocksum) {
    __shared__ int s[256];
    int t = threadIdx.x;
    s[t] = counts[blockIdx.x * 256 + t];
    __syncthreads();
    for (int d = 128; d > 0; d >>= 1) {
        if (t < d) s[t] += s[t + d];
        __syncthreads();
    }
    if (t == 0) blocksum[blockIdx.x] = s[0];
}

__global__ void k_scan2(const int* __restrict__ blocksum, int* __restrict__ blockoff) {
    __shared__ int s[256];
    int t = threadIdx.x;
    int v = (t < NBLK) ? blocksum[t] : 0;
    s[t] = v;
    __syncthreads();
    for (int d = 1; d < 256; d <<= 1) {
        int x = (t >= d) ? s[t - d] : 0;
        __syncthreads();
        s[t] += x;
        __syncthreads();
    }
    if (t < NBLK) blockoff[t] = s[t] - v;   // exclusive
}

__global__ void k_scan3(const int* __restrict__ counts, const int* __restrict__ blockoff,
                        int* __restrict__ row_start, int* __restrict__ cursor) {
    __shared__ int s[256];
    int t = threadIdx.x;
    int i = blockIdx.x * 256 + t;
    int v = counts[i];
    s[t] = v;
    __syncthreads();
    for (int d = 1; d < 256; d <<= 1) {
        int x = (t >= d) ? s[t - d] : 0;
        __syncthreads();
        s[t] += x;
        __syncthreads();
    }
    int excl = s[t] - v + blockoff[blockIdx.x];
    row_start[i] = excl;
    cursor[i] = excl;
}

__global__ void k_scatter(const int* __restrict__ edge_src, const int* __restrict__ edge_dst,
                          const int* __restrict__ edge_type, int* __restrict__ cursor,
                          int* __restrict__ sorted_src, int* __restrict__ sorted_type) {
    int e = blockIdx.x * 256 + threadIdx.x;
    if (e < N_EDGES) {
        int d = edge_dst[e];
        int pos = atomicAdd(&cursor[d], 1);
        sorted_src[pos] = edge_src[e];
        sorted_type[pos] = edge_type[e];
    }
}

// ---------------- G = features @ W1e_bot   [N,512] bf16 ----------------
__global__ __launch_bounds__(256) void k_gemm_G(const unsigned short* __restrict__ fb,
                                                const unsigned short* __restrict__ W1ebT,
                                                unsigned short* __restrict__ G) {
    __shared__ unsigned short fbs[64 * 128];
    int t = threadIdx.x;
    int mbase = blockIdx.x * 64;
    int nbase = blockIdx.y * 128;
    {
        int row = t >> 2, seg = t & 3;
        int node = mbase + row; if (node >= N_NODES) node = N_NODES - 1;
        const unsigned short* p = &fb[node * 128 + seg * 32];
        #pragma unroll
        for (int i = 0; i < 4; ++i) {
            int c = seg * 4 + i;
            int cp = c ^ (row & 7);
            *(short8*)&fbs[row * 128 + cp * 8] = *(const short8*)&p[i * 8];
        }
    }
    __syncthreads();
    int lane = t & 63, wave = t >> 6;
    int r = lane & 15, quad = lane >> 4;
    floatx4 acc[8];
    #pragma unroll
    for (int i = 0; i < 8; ++i) acc[i] = (floatx4){0.f, 0.f, 0.f, 0.f};
    #pragma unroll
    for (int ks = 0; ks < 4; ++ks) {
        int row = wave * 16 + r;
        int cp = (ks * 4 + quad) ^ (row & 7);
        short8 a = *(const short8*)&fbs[row * 128 + cp * 8];
        int k0 = ks * 32 + quad * 8;
        #pragma unroll
        for (int ct = 0; ct < 8; ++ct) {
            short8 b = *(const short8*)&W1ebT[(nbase + ct * 16 + r) * 128 + k0];
            acc[ct] = __builtin_amdgcn_mfma_f32_16x16x32_bf16(a, b, acc[ct], 0, 0, 0);
        }
    }
    #pragma unroll
    for (int ct = 0; ct < 8; ++ct)
        #pragma unroll
        for (int p = 0; p < 4; ++p) {
            int node = mbase + wave * 16 + quad * 4 + p;
            if (node < N_NODES)
                G[node * 512 + nbase + ct * 16 + r] = f2bf(acc[ct][p]);
        }
}

// ---------------- self MLP: out[:, :128] ----------------
__global__ __launch_bounds__(256) void k_self(const unsigned short* __restrict__ fb,
                                              const unsigned short* __restrict__ W1sT,
                                              const float* __restrict__ b1s,
                                              const unsigned short* __restrict__ W2sT,
                                              const float* __restrict__ b2s,
                                              float* __restrict__ out) {
    __shared__ unsigned short fbs[64 * 128];
    __shared__ unsigned short hss[64 * 256];
    int t = threadIdx.x;
    int mbase = blockIdx.x * 64;
    {
        int row = t >> 2, seg = t & 3;
        int node = mbase + row; if (node >= N_NODES) node = N_NODES - 1;
        const unsigned short* p = &fb[node * 128 + seg * 32];
        #pragma unroll
        for (int i = 0; i < 4; ++i) {
            int c = seg * 4 + i;
            int cp = c ^ (row & 7);
            *(short8*)&fbs[row * 128 + cp * 8] = *(const short8*)&p[i * 8];
        }
    }
    __syncthreads();
    int lane = t & 63, wave = t >> 6;
    int r = lane & 15, quad = lane >> 4;

    floatx4 acc1[16];
    #pragma unroll
    for (int i = 0; i < 16; ++i) acc1[i] = (floatx4){0.f, 0.f, 0.f, 0.f};
    #pragma unroll
    for (int ks = 0; ks < 4; ++ks) {
        int row = wave * 16 + r;
        int cp = (ks * 4 + quad) ^ (row & 7);
        short8 a = *(const short8*)&fbs[row * 128 + cp * 8];
        int k0 = ks * 32 + quad * 8;
        #pragma unroll
        for (int ct = 0; ct < 16; ++ct) {
            short8 b = *(const short8*)&W1sT[(ct * 16 + r) * 128 + k0];
            acc1[ct] = __builtin_amdgcn_mfma_f32_16x16x32_bf16(a, b, acc1[ct], 0, 0, 0);
        }
    }
    #pragma unroll
    for (int ct = 0; ct < 16; ++ct)
        #pragma unroll
        for (int p = 0; p < 4; ++p) {
            int lrow = wave * 16 + quad * 4 + p;
            int col = ct * 16 + r;
            float v = fmaxf(acc1[ct][p] + b1s[col], 0.f);
            int cp = (col >> 3) ^ (lrow & 7);
            hss[lrow * 256 + cp * 8 + (col & 7)] = f2bf(v);
        }
    __syncthreads();

    floatx4 acc2[8];
    #pragma unroll
    for (int i = 0; i < 8; ++i) acc2[i] = (floatx4){0.f, 0.f, 0.f, 0.f};
    #pragma unroll
    for (int ks = 0; ks < 8; ++ks) {
        int row = wave * 16 + r;
        int cp = (ks * 4 + quad) ^ (row & 7);
        short8 a = *(const short8*)&hss[row * 256 + cp * 8];
        int k0 = ks * 32 + quad * 8;
        #pragma unroll
        for (int ct = 0; ct < 8; ++ct) {
            short8 b = *(const short8*)&W2sT[(ct * 16 + r) * 256 + k0];
            acc2[ct] = __builtin_amdgcn_mfma_f32_16x16x32_bf16(a, b, acc2[ct], 0, 0, 0);
        }
    }
    #pragma unroll
    for (int ct = 0; ct < 8; ++ct)
        #pragma unroll
        for (int p = 0; p < 4; ++p) {
            int node = mbase + wave * 16 + quad * 4 + p;
            if (node < N_NODES) {
                int col = ct * 16 + r;
                out[(size_t)node * 256 + col] = acc2[ct][p] + b2s[col];
            }
        }
}

// ---------------- aggregation: H[n] = sum_e relu(G[src]+T[type])   [N,512] bf16 ----------------
// wave-per-node, no LDS, 4-edge unroll for memory-level parallelism.
__global__ __launch_bounds__(256) void k_agg(const unsigned short* __restrict__ G,
                                             const unsigned short* __restrict__ Tb,
                                             const int* __restrict__ row_start,
                                             const int* __restrict__ sorted_src,
                                             const int* __restrict__ sorted_type,
                                             unsigned short* __restrict__ H) {
    int t = threadIdx.x, lane = t & 63, wave = t >> 6;
    int node = blockIdx.x * 4 + wave;
    if (node >= N_NODES) return;
    int beg = row_start[node], end = row_start[node + 1];
    float acc[8] = {0.f, 0.f, 0.f, 0.f, 0.f, 0.f, 0.f, 0.f};
    int off = lane * 8;
    int e = beg;
    for (; e + 4 <= end; e += 4) {
        int s0 = sorted_src[e],     s1 = sorted_src[e + 1];
        int s2 = sorted_src[e + 2], s3 = sorted_src[e + 3];
        int y0 = sorted_type[e],     y1 = sorted_type[e + 1];
        int y2 = sorted_type[e + 2], y3 = sorted_type[e + 3];
        short8 g0 = *(const short8*)&G[(size_t)s0 * 512 + off];
        short8 g1 = *(const short8*)&G[(size_t)s1 * 512 + off];
        short8 g2 = *(const short8*)&G[(size_t)s2 * 512 + off];
        short8 g3 = *(const short8*)&G[(size_t)s3 * 512 + off];
        short8 v0 = *(const short8*)&Tb[y0 * 512 + off];
        short8 v1 = *(const short8*)&Tb[y1 * 512 + off];
        short8 v2 = *(const short8*)&Tb[y2 * 512 + off];
        short8 v3 = *(const short8*)&Tb[y3 * 512 + off];
        #pragma unroll
        for (int i = 0; i < 8; ++i) {
            acc[i] += fmaxf(bf2f((unsigned short)g0[i]) + bf2f((unsigned short)v0[i]), 0.f);
            acc[i] += fmaxf(bf2f((unsigned short)g1[i]) + bf2f((unsigned short)v1[i]), 0.f);
            acc[i] += fmaxf(bf2f((unsigned short)g2[i]) + bf2f((unsigned short)v2[i]), 0.f);
            acc[i] += fmaxf(bf2f((unsigned short)g3[i]) + bf2f((unsigned short)v3[i]), 0.f);
        }
    }
    for (; e < end; ++e) {
        int s0 = sorted_src[e];
        int y0 = sorted_type[e];
        short8 g0 = *(const short8*)&G[(size_t)s0 * 512 + off];
        short8 v0 = *(const short8*)&Tb[y0 * 512 + off];
        #pragma unroll
        for (int i = 0; i < 8; ++i)
            acc[i] += fmaxf(bf2f((unsigned short)g0[i]) + bf2f((unsigned short)v0[i]), 0.f);
    }
    short8 hv;
    #pragma unroll
    for (int i = 0; i < 8; ++i) hv[i] = (short)f2bf(acc[i]);
    *(short8*)&H[(size_t)node * 512 + off] = hv;
}

// ---------------- out[:,128:] = H @ W2e + deg*b2e ----------------
__global__ __launch_bounds__(256) void k_gemm_H(const unsigned short* __restrict__ H,
                                                const int* __restrict__ row_start,
                                                const unsigned short* __restrict__ W2eT,
                                                const float* __restrict__ b2e,
                                                float* __restrict__ out) {
    __shared__ unsigned short hls[64 * 512];   // 64 KB
    int t = threadIdx.x;
    int nbase = blockIdx.x * 64;
    {
        int row = t >> 2, seg = t & 3;
        int node = nbase + row; if (node >= N_NODES) node = N_NODES - 1;
        const unsigned short* p = &H[(size_t)node * 512 + seg * 128];
        #pragma unroll
        for (int i = 0; i < 16; ++i) {
            int c = seg * 16 + i;
            int cp = c ^ (row & 7);
            *(short8*)&hls[row * 512 + cp * 8] = *(const short8*)&p[i * 8];
        }
    }
    __syncthreads();
    int lane = t & 63, wave = t >> 6;
    int r = lane & 15, quad = lane >> 4;
    floatx4 acc[8];
    #pragma unroll
    for (int i = 0; i < 8; ++i) acc[i] = (floatx4){0.f, 0.f, 0.f, 0.f};
    #pragma unroll
    for (int ks = 0; ks < 16; ++ks) {
        int row = wave * 16 + r;
        int cp = (ks * 4 + quad) ^ (row & 7);
        short8 a = *(const short8*)&hls[row * 512 + cp * 8];
        int k0 = ks * 32 + quad * 8;
        #pragma unroll
        for (int ct = 0; ct < 8; ++ct) {
            short8 b = *(const short8*)&W2eT[(ct * 16 + r) * 512 + k0];
            acc[ct] = __builtin_amdgcn_mfma_f32_16x16x32_bf16(a, b, acc[ct], 0, 0, 0);
        }
    }
    float b2v[8];
    #pragma unroll
    for (int ct = 0; ct < 8; ++ct) b2v[ct] = b2e[ct * 16 + r];
    #pragma unroll
    for (int p = 0; p < 4; ++p) {
        int row = wave * 16 + quad * 4 + p;
        int node = nbase + row;
        if (node < N_NODES) {
            float dg = (float)(row_start[node + 1] - row_start[node]);
            float* op = &out[(size_t)node * 256 + 128];
            #pragma unroll
            for (int ct = 0; ct < 8; ++ct)
                op[ct * 16 + r] = acc[ct][p] + dg * b2v[ct];
        }
    }
}

// ---------------- launch ----------------

extern "C" void kernel_launch(void* const* d_in, const int* in_sizes, int n_in,
                              void* d_out, int out_size, void* d_ws, size_t ws_size,
                              hipStream_t stream) {
    const float* features  = (const float*)d_in[0];
    const int*   edge_src  = (const int*)d_in[1];
    const int*   edge_dst  = (const int*)d_in[2];
    const int*   edge_type = (const int*)d_in[3];
    const float* e_emb     = (const float*)d_in[4];
    const float* W1e       = (const float*)d_in[5];
    const float* b1e       = (const float*)d_in[6];
    const float* W2e       = (const float*)d_in[7];
    const float* b2e       = (const float*)d_in[8];
    const float* W1s       = (const float*)d_in[9];
    const float* b1s       = (const float*)d_in[10];
    const float* W2s       = (const float*)d_in[11];
    const float* b2s       = (const float*)d_in[12];
    float* out = (float*)d_out;

    char* ws = (char*)d_ws;
    size_t off = 0;
    auto alloc = [&](size_t bytes) {
        char* p = ws + off;
        off += (bytes + 255) & ~(size_t)255;
        return p;
    };
    unsigned short* fb       = (unsigned short*)alloc((size_t)N_NODES * 128 * 2);
    unsigned short* G        = (unsigned short*)alloc((size_t)N_NODES * 512 * 2);
    unsigned short* H        = (unsigned short*)alloc((size_t)N_NODES * 512 * 2);
    unsigned short* Tb       = (unsigned short*)alloc(16 * 512 * 2);
    unsigned short* W1ebT    = (unsigned short*)alloc(512 * 128 * 2);
    unsigned short* W2eT     = (unsigned short*)alloc(128 * 512 * 2);
    unsigned short* W1sT     = (unsigned short*)alloc(256 * 128 * 2);
    unsigned short* W2sT     = (unsigned short*)alloc(128 * 256 * 2);
    int* counts     = (int*)alloc((size_t)N_PAD * 4);
    int* row_start  = (int*)alloc((size_t)N_PAD * 4);
    int* cursor     = (int*)alloc((size_t)N_PAD * 4);
    int* blocksum   = (int*)alloc(256 * 4);
    int* blockoff   = (int*)alloc(256 * 4);
    int* sorted_src = (int*)alloc((size_t)N_EDGES * 4);
    int* sorted_typ = (int*)alloc((size_t)N_EDGES * 4);

    hipMemsetAsync(counts, 0, (size_t)N_PAD * 4, stream);

    k_cvt_feat<<<1024, 256, 0, stream>>>(features, fb, N_NODES * 128);
    k_prep_w<<<800, 256, 0, stream>>>(e_emb, W1e, b1e, W2e, W1s, W2s,
                                      Tb, W1ebT, W2eT, W1sT, W2sT);

    k_hist<<<(N_EDGES + 255) / 256, 256, 0, stream>>>(edge_dst, counts);
    k_scan1<<<NBLK, 256, 0, stream>>>(counts, blocksum);
    k_scan2<<<1, 256, 0, stream>>>(blocksum, blockoff);
    k_scan3<<<NBLK, 256, 0, stream>>>(counts, blockoff, row_start, cursor);
    k_scatter<<<(N_EDGES + 255) / 256, 256, 0, stream>>>(edge_src, edge_dst, edge_type,
                                                         cursor, sorted_src, sorted_typ);

    k_gemm_G<<<dim3((N_NODES + 63) / 64, 4), 256, 0, stream>>>(fb, W1ebT, G);
    k_self<<<(N_NODES + 63) / 64, 256, 0, stream>>>(fb, W1sT, b1s, W2sT, b2s, out);
    k_agg<<<(N_NODES + 3) / 4, 256, 0, stream>>>(G, Tb, row_start, sorted_src, sorted_typ, H);
    k_gemm_H<<<(N_NODES + 63) / 64, 256, 0, stream>>>(H, row_start, W2eT, b2e, out);
}

// Round 4
// 299.363 us; speedup vs baseline: 2.6555x; 1.4593x over previous
//
#include <hip/hip_runtime.h>

#define N_NODES 50000
#define N_EDGES 400000
#define N_TILES 782          // ceil(50000/64)
#define GRID_G  512

#define N_PAD   50176        // 196 * 256
#define NBLK    196

typedef __attribute__((ext_vector_type(8))) short short8;
typedef __attribute__((ext_vector_type(4))) float floatx4;

__device__ __forceinline__ float bf2f(unsigned short u) {
    union { unsigned int i; float f; } v; v.i = ((unsigned int)u) << 16; return v.f;
}
__device__ __forceinline__ unsigned short f2bf(float f) {
    union { float f; unsigned int i; } v; v.f = f;
    unsigned int b = v.i;
    return (unsigned short)((b + 0x7FFFu + ((b >> 16) & 1u)) >> 16);
}

// stage one 64-row x 128-col f32 tile -> swizzled bf16 LDS tile (16 KB)
__device__ __forceinline__ void stage_feat(const float* __restrict__ features,
                                           unsigned short* __restrict__ fbs,
                                           int mbase, int t) {
    int row = t >> 2, seg = t & 3;
    int node = mbase + row; if (node >= N_NODES) node = N_NODES - 1;
    const float* p = &features[(size_t)node * 128 + seg * 32];
    #pragma unroll
    for (int i = 0; i < 4; ++i) {
        float4 x = *(const float4*)&p[i * 8];
        float4 y = *(const float4*)&p[i * 8 + 4];
        short8 hv;
        hv[0] = (short)f2bf(x.x); hv[1] = (short)f2bf(x.y);
        hv[2] = (short)f2bf(x.z); hv[3] = (short)f2bf(x.w);
        hv[4] = (short)f2bf(y.x); hv[5] = (short)f2bf(y.y);
        hv[6] = (short)f2bf(y.z); hv[7] = (short)f2bf(y.w);
        int c = seg * 4 + i;
        int cp = c ^ (row & 7);
        *(short8*)&fbs[row * 128 + cp * 8] = hv;
    }
}

// ---------------- weight prep (fused) ----------------
//   [0,8192)        Tb[16][512] = bf16(e_emb @ W1e_top + b1e)
//   [8192,73728)    W1ebT [512][128]
//   [73728,139264)  W2eT  [128][512]
//   [139264,172032) W1sT  [256][128]
//   [172032,204800) W2sT  [128][256]
__device__ __forceinline__ void tr_seg(const float* __restrict__ src, unsigned short* __restrict__ dst,
                                       int K, int Ncols, int idx) {
    int c = idx / K, k = idx - c * K;
    dst[idx] = f2bf(src[k * Ncols + c]);
}

__global__ void k_prep_w(const float* __restrict__ e_emb, const float* __restrict__ W1e,
                         const float* __restrict__ b1e, const float* __restrict__ W2e,
                         const float* __restrict__ W1s, const float* __restrict__ W2s,
                         unsigned short* __restrict__ Tb, unsigned short* __restrict__ W1ebT,
                         unsigned short* __restrict__ W2eT, unsigned short* __restrict__ W1sT,
                         unsigned short* __restrict__ W2sT) {
    int tid = blockIdx.x * 256 + threadIdx.x;
    if (tid < 8192) {
        int typ = tid >> 9, col = tid & 511;
        float acc = b1e[col];
        for (int k = 0; k < 128; ++k)
            acc += e_emb[typ * 128 + k] * W1e[k * 512 + col];
        Tb[tid] = f2bf(acc);
    } else if (tid < 73728) {
        tr_seg(W1e + 128 * 512, W1ebT, 128, 512, tid - 8192);
    } else if (tid < 139264) {
        tr_seg(W2e, W2eT, 512, 128, tid - 73728);
    } else if (tid < 172032) {
        tr_seg(W1s, W1sT, 128, 256, tid - 139264);
    } else if (tid < 204800) {
        tr_seg(W2s, W2sT, 256, 128, tid - 172032);
    }
}

// ---------------- counting sort of edges by dst ----------------

__global__ void k_hist(const int* __restrict__ edge_dst, int* __restrict__ counts) {
    int e = blockIdx.x * 256 + threadIdx.x;
    if (e < N_EDGES) atomicAdd(&counts[edge_dst[e]], 1);
}

__global__ void k_scan1(const int* __restrict__ counts, int* __restrict__ blocksum) {
    __shared__ int s[256];
    int t = threadIdx.x;
    s[t] = counts[blockIdx.x * 256 + t];
    __syncthreads();
    for (int d = 128; d > 0; d >>= 1) {
        if (t < d) s[t] += s[t + d];
        __syncthreads();
    }
    if (t == 0) blocksum[blockIdx.x] = s[0];
}

__global__ void k_scan2(const int* __restrict__ blocksum, int* __restrict__ blockoff) {
    __shared__ int s[256];
    int t = threadIdx.x;
    int v = (t < NBLK) ? blocksum[t] : 0;
    s[t] = v;
    __syncthreads();
    for (int d = 1; d < 256; d <<= 1) {
        int x = (t >= d) ? s[t - d] : 0;
        __syncthreads();
        s[t] += x;
        __syncthreads();
    }
    if (t < NBLK) blockoff[t] = s[t] - v;
}

__global__ void k_scan3(const int* __restrict__ counts, const int* __restrict__ blockoff,
                        int* __restrict__ row_start, int* __restrict__ cursor) {
    __shared__ int s[256];
    int t = threadIdx.x;
    int i = blockIdx.x * 256 + t;
    int v = counts[i];
    s[t] = v;
    __syncthreads();
    for (int d = 1; d < 256; d <<= 1) {
        int x = (t >= d) ? s[t - d] : 0;
        __syncthreads();
        s[t] += x;
        __syncthreads();
    }
    int excl = s[t] - v + blockoff[blockIdx.x];
    row_start[i] = excl;
    cursor[i] = excl;
}

__global__ void k_scatter(const int* __restrict__ edge_src, const int* __restrict__ edge_dst,
                          const int* __restrict__ edge_type, int* __restrict__ cursor,
                          int* __restrict__ sorted_src, int* __restrict__ sorted_type) {
    int e = blockIdx.x * 256 + threadIdx.x;
    if (e < N_EDGES) {
        int d = edge_dst[e];
        int pos = atomicAdd(&cursor[d], 1);
        sorted_src[pos] = edge_src[e];
        sorted_type[pos] = edge_type[e];
    }
}

// ---------------- G = features @ W1e_bot   [N,512] bf16 ----------------
// B-fragments hoisted to registers (wave w owns cols [w*128, w*128+128)),
// grid-stride over 64-row tiles. Inner loop: ds_read + MFMA only.
__global__ __launch_bounds__(256, 2) void k_gemm_G(const float* __restrict__ features,
                                                   const unsigned short* __restrict__ W1ebT,
                                                   unsigned short* __restrict__ G) {
    __shared__ unsigned short fbs[64 * 128];
    int t = threadIdx.x, lane = t & 63, wave = t >> 6;
    int r = lane & 15, quad = lane >> 4;

    short8 bfrag[8][4];
    #pragma unroll
    for (int ct = 0; ct < 8; ++ct)
        #pragma unroll
        for (int ks = 0; ks < 4; ++ks)
            bfrag[ct][ks] = *(const short8*)&W1ebT[(wave * 128 + ct * 16 + r) * 128 + ks * 32 + quad * 8];

    for (int tile = blockIdx.x; tile < N_TILES; tile += GRID_G) {
        int mbase = tile * 64;
        stage_feat(features, fbs, mbase, t);
        __syncthreads();
        #pragma unroll
        for (int m = 0; m < 4; ++m) {
            floatx4 acc[8];
            #pragma unroll
            for (int i = 0; i < 8; ++i) acc[i] = (floatx4){0.f, 0.f, 0.f, 0.f};
            #pragma unroll
            for (int ks = 0; ks < 4; ++ks) {
                int row = m * 16 + r;
                int cp = (ks * 4 + quad) ^ (row & 7);
                short8 a = *(const short8*)&fbs[row * 128 + cp * 8];
                #pragma unroll
                for (int ct = 0; ct < 8; ++ct)
                    acc[ct] = __builtin_amdgcn_mfma_f32_16x16x32_bf16(a, bfrag[ct][ks], acc[ct], 0, 0, 0);
            }
            #pragma unroll
            for (int ct = 0; ct < 8; ++ct)
                #pragma unroll
                for (int p = 0; p < 4; ++p) {
                    int node = mbase + m * 16 + quad * 4 + p;
                    if (node < N_NODES)
                        G[(size_t)node * 512 + wave * 128 + ct * 16 + r] = f2bf(acc[ct][p]);
                }
        }
        __syncthreads();
    }
}

// ---------------- self MLP: out[:, :128] ----------------
// layer1: wave owns 64 of 256 hidden cols; layer2: wave owns 32 of 128 out cols.
__global__ __launch_bounds__(256, 2) void k_self(const float* __restrict__ features,
                                                 const unsigned short* __restrict__ W1sT,
                                                 const float* __restrict__ b1s,
                                                 const unsigned short* __restrict__ W2sT,
                                                 const float* __restrict__ b2s,
                                                 float* __restrict__ out) {
    __shared__ unsigned short fbs[64 * 128];
    __shared__ unsigned short hss[64 * 256];
    int t = threadIdx.x, lane = t & 63, wave = t >> 6;
    int r = lane & 15, quad = lane >> 4;

    short8 b1f[4][4];
    #pragma unroll
    for (int ct = 0; ct < 4; ++ct)
        #pragma unroll
        for (int ks = 0; ks < 4; ++ks)
            b1f[ct][ks] = *(const short8*)&W1sT[(wave * 64 + ct * 16 + r) * 128 + ks * 32 + quad * 8];
    short8 b2f[2][8];
    #pragma unroll
    for (int ct = 0; ct < 2; ++ct)
        #pragma unroll
        for (int ks = 0; ks < 8; ++ks)
            b2f[ct][ks] = *(const short8*)&W2sT[(wave * 32 + ct * 16 + r) * 256 + ks * 32 + quad * 8];
    float bias1[4], bias2[2];
    #pragma unroll
    for (int ct = 0; ct < 4; ++ct) bias1[ct] = b1s[wave * 64 + ct * 16 + r];
    #pragma unroll
    for (int ct = 0; ct < 2; ++ct) bias2[ct] = b2s[wave * 32 + ct * 16 + r];

    for (int tile = blockIdx.x; tile < N_TILES; tile += GRID_G) {
        int mbase = tile * 64;
        stage_feat(features, fbs, mbase, t);
        __syncthreads();

        // layer 1 -> hss (swizzled bf16)
        #pragma unroll
        for (int m = 0; m < 4; ++m) {
            floatx4 acc[4];
            #pragma unroll
            for (int i = 0; i < 4; ++i) acc[i] = (floatx4){0.f, 0.f, 0.f, 0.f};
            #pragma unroll
            for (int ks = 0; ks < 4; ++ks) {
                int row = m * 16 + r;
                int cp = (ks * 4 + quad) ^ (row & 7);
                short8 a = *(const short8*)&fbs[row * 128 + cp * 8];
                #pragma unroll
                for (int ct = 0; ct < 4; ++ct)
                    acc[ct] = __builtin_amdgcn_mfma_f32_16x16x32_bf16(a, b1f[ct][ks], acc[ct], 0, 0, 0);
            }
            #pragma unroll
            for (int ct = 0; ct < 4; ++ct)
                #pragma unroll
                for (int p = 0; p < 4; ++p) {
                    int lrow = m * 16 + quad * 4 + p;
                    int col = wave * 64 + ct * 16 + r;
                    float v = fmaxf(acc[ct][p] + bias1[ct], 0.f);
                    int cp = (col >> 3) ^ (lrow & 7);
                    hss[lrow * 256 + cp * 8 + (col & 7)] = f2bf(v);
                }
        }
        __syncthreads();

        // layer 2 -> out[:, :128]
        #pragma unroll
        for (int m = 0; m < 4; ++m) {
            floatx4 acc[2];
            #pragma unroll
            for (int i = 0; i < 2; ++i) acc[i] = (floatx4){0.f, 0.f, 0.f, 0.f};
            #pragma unroll
            for (int ks = 0; ks < 8; ++ks) {
                int row = m * 16 + r;
                int cp = (ks * 4 + quad) ^ (row & 7);
                short8 a = *(const short8*)&hss[row * 256 + cp * 8];
                #pragma unroll
                for (int ct = 0; ct < 2; ++ct)
                    acc[ct] = __builtin_amdgcn_mfma_f32_16x16x32_bf16(a, b2f[ct][ks], acc[ct], 0, 0, 0);
            }
            #pragma unroll
            for (int ct = 0; ct < 2; ++ct)
                #pragma unroll
                for (int p = 0; p < 4; ++p) {
                    int node = mbase + m * 16 + quad * 4 + p;
                    if (node < N_NODES)
                        out[(size_t)node * 256 + wave * 32 + ct * 16 + r] = acc[ct][p] + bias2[ct];
                }
        }
        __syncthreads();
    }
}

// ---------------- aggregation: H[n] = sum_e relu(G[src]+T[type])   [N,512] bf16 ----------------
__global__ __launch_bounds__(256) void k_agg(const unsigned short* __restrict__ G,
                                             const unsigned short* __restrict__ Tb,
                                             const int* __restrict__ row_start,
                                             const int* __restrict__ sorted_src,
                                             const int* __restrict__ sorted_type,
                                             unsigned short* __restrict__ H) {
    int t = threadIdx.x, lane = t & 63, wave = t >> 6;
    int node = blockIdx.x * 4 + wave;
    if (node >= N_NODES) return;
    int beg = row_start[node], end = row_start[node + 1];
    float acc[8] = {0.f, 0.f, 0.f, 0.f, 0.f, 0.f, 0.f, 0.f};
    int off = lane * 8;
    int e = beg;
    for (; e + 4 <= end; e += 4) {
        int s0 = sorted_src[e],     s1 = sorted_src[e + 1];
        int s2 = sorted_src[e + 2], s3 = sorted_src[e + 3];
        int y0 = sorted_type[e],     y1 = sorted_type[e + 1];
        int y2 = sorted_type[e + 2], y3 = sorted_type[e + 3];
        short8 g0 = *(const short8*)&G[(size_t)s0 * 512 + off];
        short8 g1 = *(const short8*)&G[(size_t)s1 * 512 + off];
        short8 g2 = *(const short8*)&G[(size_t)s2 * 512 + off];
        short8 g3 = *(const short8*)&G[(size_t)s3 * 512 + off];
        short8 v0 = *(const short8*)&Tb[y0 * 512 + off];
        short8 v1 = *(const short8*)&Tb[y1 * 512 + off];
        short8 v2 = *(const short8*)&Tb[y2 * 512 + off];
        short8 v3 = *(const short8*)&Tb[y3 * 512 + off];
        #pragma unroll
        for (int i = 0; i < 8; ++i) {
            acc[i] += fmaxf(bf2f((unsigned short)g0[i]) + bf2f((unsigned short)v0[i]), 0.f);
            acc[i] += fmaxf(bf2f((unsigned short)g1[i]) + bf2f((unsigned short)v1[i]), 0.f);
            acc[i] += fmaxf(bf2f((unsigned short)g2[i]) + bf2f((unsigned short)v2[i]), 0.f);
            acc[i] += fmaxf(bf2f((unsigned short)g3[i]) + bf2f((unsigned short)v3[i]), 0.f);
        }
    }
    for (; e < end; ++e) {
        int s0 = sorted_src[e];
        int y0 = sorted_type[e];
        short8 g0 = *(const short8*)&G[(size_t)s0 * 512 + off];
        short8 v0 = *(const short8*)&Tb[y0 * 512 + off];
        #pragma unroll
        for (int i = 0; i < 8; ++i)
            acc[i] += fmaxf(bf2f((unsigned short)g0[i]) + bf2f((unsigned short)v0[i]), 0.f);
    }
    short8 hv;
    #pragma unroll
    for (int i = 0; i < 8; ++i) hv[i] = (short)f2bf(acc[i]);
    *(short8*)&H[(size_t)node * 512 + off] = hv;
}

// ---------------- out[:,128:] = H @ W2e + deg*b2e ----------------
// wave owns 32 of 128 out cols; B (K=512) in 128 VGPRs; grid-stride tiles.
__global__ __launch_bounds__(256, 2) void k_gemm_H(const unsigned short* __restrict__ H,
                                                   const int* __restrict__ row_start,
                                                   const unsigned short* __restrict__ W2eT,
                                                   const float* __restrict__ b2e,
                                                   float* __restrict__ out) {
    __shared__ unsigned short hls[64 * 512];   // 64 KB
    int t = threadIdx.x, lane = t & 63, wave = t >> 6;
    int r = lane & 15, quad = lane >> 4;

    short8 bf[2][16];
    #pragma unroll
    for (int ct = 0; ct < 2; ++ct)
        #pragma unroll
        for (int ks = 0; ks < 16; ++ks)
            bf[ct][ks] = *(const short8*)&W2eT[(wave * 32 + ct * 16 + r) * 512 + ks * 32 + quad * 8];
    float bias[2];
    #pragma unroll
    for (int ct = 0; ct < 2; ++ct) bias[ct] = b2e[wave * 32 + ct * 16 + r];

    for (int tile = blockIdx.x; tile < N_TILES; tile += GRID_G) {
        int nbase = tile * 64;
        {
            int row = t >> 2, seg = t & 3;
            int node = nbase + row; if (node >= N_NODES) node = N_NODES - 1;
            const unsigned short* p = &H[(size_t)node * 512 + seg * 128];
            #pragma unroll
            for (int i = 0; i < 16; ++i) {
                int c = seg * 16 + i;
                int cp = c ^ (row & 7);
                *(short8*)&hls[row * 512 + cp * 8] = *(const short8*)&p[i * 8];
            }
        }
        __syncthreads();
        #pragma unroll
        for (int m = 0; m < 4; ++m) {
            floatx4 acc[2];
            #pragma unroll
            for (int i = 0; i < 2; ++i) acc[i] = (floatx4){0.f, 0.f, 0.f, 0.f};
            #pragma unroll
            for (int ks = 0; ks < 16; ++ks) {
                int row = m * 16 + r;
                int cp = (ks * 4 + quad) ^ (row & 7);
                short8 a = *(const short8*)&hls[row * 512 + cp * 8];
                #pragma unroll
                for (int ct = 0; ct < 2; ++ct)
                    acc[ct] = __builtin_amdgcn_mfma_f32_16x16x32_bf16(a, bf[ct][ks], acc[ct], 0, 0, 0);
            }
            #pragma unroll
            for (int p = 0; p < 4; ++p) {
                int node = nbase + m * 16 + quad * 4 + p;
                if (node < N_NODES) {
                    float dg = (float)(row_start[node + 1] - row_start[node]);
                    #pragma unroll
                    for (int ct = 0; ct < 2; ++ct)
                        out[(size_t)node * 256 + 128 + wave * 32 + ct * 16 + r] = acc[ct][p] + dg * bias[ct];
                }
            }
        }
        __syncthreads();
    }
}

// ---------------- launch ----------------

extern "C" void kernel_launch(void* const* d_in, const int* in_sizes, int n_in,
                              void* d_out, int out_size, void* d_ws, size_t ws_size,
                              hipStream_t stream) {
    const float* features  = (const float*)d_in[0];
    const int*   edge_src  = (const int*)d_in[1];
    const int*   edge_dst  = (const int*)d_in[2];
    const int*   edge_type = (const int*)d_in[3];
    const float* e_emb     = (const float*)d_in[4];
    const float* W1e       = (const float*)d_in[5];
    const float* b1e       = (const float*)d_in[6];
    const float* W2e       = (const float*)d_in[7];
    const float* b2e       = (const float*)d_in[8];
    const float* W1s       = (const float*)d_in[9];
    const float* b1s       = (const float*)d_in[10];
    const float* W2s       = (const float*)d_in[11];
    const float* b2s       = (const float*)d_in[12];
    float* out = (float*)d_out;

    char* ws = (char*)d_ws;
    size_t off = 0;
    auto alloc = [&](size_t bytes) {
        char* p = ws + off;
        off += (bytes + 255) & ~(size_t)255;
        return p;
    };
    unsigned short* G        = (unsigned short*)alloc((size_t)N_NODES * 512 * 2);
    unsigned short* H        = (unsigned short*)alloc((size_t)N_NODES * 512 * 2);
    unsigned short* Tb       = (unsigned short*)alloc(16 * 512 * 2);
    unsigned short* W1ebT    = (unsigned short*)alloc(512 * 128 * 2);
    unsigned short* W2eT     = (unsigned short*)alloc(128 * 512 * 2);
    unsigned short* W1sT     = (unsigned short*)alloc(256 * 128 * 2);
    unsigned short* W2sT     = (unsigned short*)alloc(128 * 256 * 2);
    int* counts     = (int*)alloc((size_t)N_PAD * 4);
    int* row_start  = (int*)alloc((size_t)N_PAD * 4);
    int* cursor     = (int*)alloc((size_t)N_PAD * 4);
    int* blocksum   = (int*)alloc(256 * 4);
    int* blockoff   = (int*)alloc(256 * 4);
    int* sorted_src = (int*)alloc((size_t)N_EDGES * 4);
    int* sorted_typ = (int*)alloc((size_t)N_EDGES * 4);

    hipMemsetAsync(counts, 0, (size_t)N_PAD * 4, stream);

    k_prep_w<<<800, 256, 0, stream>>>(e_emb, W1e, b1e, W2e, W1s, W2s,
                                      Tb, W1ebT, W2eT, W1sT, W2sT);

    k_hist<<<(N_EDGES + 255) / 256, 256, 0, stream>>>(edge_dst, counts);
    k_scan1<<<NBLK, 256, 0, stream>>>(counts, blocksum);
    k_scan2<<<1, 256, 0, stream>>>(blocksum, blockoff);
    k_scan3<<<NBLK, 256, 0, stream>>>(counts, blockoff, row_start, cursor);
    k_scatter<<<(N_EDGES + 255) / 256, 256, 0, stream>>>(edge_src, edge_dst, edge_type,
                                                         cursor, sorted_src, sorted_typ);

    k_gemm_G<<<GRID_G, 256, 0, stream>>>(features, W1ebT, G);
    k_self<<<GRID_G, 256, 0, stream>>>(features, W1sT, b1s, W2sT, b2s, out);
    k_agg<<<(N_NODES + 3) / 4, 256, 0, stream>>>(G, Tb, row_start, sorted_src, sorted_typ, H);
    k_gemm_H<<<GRID_G, 256, 0, stream>>>(H, row_start, W2eT, b2e, out);
}